// Round 14
// baseline (800.501 us; speedup 1.0000x reference)
//
#include <hip/hip_runtime.h>

typedef short bf16x8 __attribute__((ext_vector_type(8)));
typedef float f32x4 __attribute__((ext_vector_type(4)));

__device__ __forceinline__ float b2f(unsigned short u) {
  union { unsigned int i; float f; } x; x.i = ((unsigned int)u) << 16; return x.f;
}
__device__ __forceinline__ unsigned short f2b(float f) {
  union { float f; unsigned int u; } x; x.f = f;
  unsigned int r = (x.u + 0x7FFFu + ((x.u >> 16) & 1u)) >> 16;
  return (unsigned short)r;
}
__device__ __forceinline__ float gelu_f(float v) {
  return 0.5f * v * (1.0f + erff(v * 0.70710678118654752440f));
}

// ------------------- setup kernels -------------------

__global__ void count_kernel(const int* __restrict__ ei, int E, int* __restrict__ cnt) {
  int e = blockIdx.x * 256 + threadIdx.x;
  if (e < E) atomicAdd(&cnt[ei[E + e]], 1);
}

__global__ void dinv_kernel(const int* __restrict__ cnt, float* __restrict__ dinv, int Nn) {
  int n = blockIdx.x * 256 + threadIdx.x;
  if (n < Nn) dinv[n] = rsqrtf((float)cnt[n] + 1.0f);  // +1 self-loop
}

// x (f32) -> bf16, 8 elems/thread
__global__ void xcast_kernel(const float* __restrict__ x, unsigned short* __restrict__ xb,
                             int total8) {
  int i = blockIdx.x * 256 + threadIdx.x;
  if (i < total8) {
    float4 a = *(const float4*)(x + (size_t)i * 8);
    float4 b = *(const float4*)(x + (size_t)i * 8 + 4);
    bf16x8 o;
    o[0] = (short)f2b(a.x); o[1] = (short)f2b(a.y); o[2] = (short)f2b(a.z); o[3] = (short)f2b(a.w);
    o[4] = (short)f2b(b.x); o[5] = (short)f2b(b.y); o[6] = (short)f2b(b.z); o[7] = (short)f2b(b.w);
    *(bf16x8*)(xb + (size_t)i * 8) = o;
  }
}

// ---- multi-block exclusive scan of cnt[0..Nn) -> rowstart/cursor (3 passes) ----

__global__ __launch_bounds__(256) void scanA_kernel(const int* __restrict__ cnt,
                                                    int* __restrict__ bsum, int Nn) {
  __shared__ int red[256];
  const int t = threadIdx.x;
  const int base = blockIdx.x * 512 + t * 2;
  int a = (base < Nn) ? cnt[base] : 0;
  int b = (base + 1 < Nn) ? cnt[base + 1] : 0;
  red[t] = a + b;
  __syncthreads();
  for (int d = 128; d > 0; d >>= 1) {
    if (t < d) red[t] += red[t + d];
    __syncthreads();
  }
  if (t == 0) bsum[blockIdx.x] = red[0];
}

__global__ __launch_bounds__(256) void scanB_kernel(const int* __restrict__ bsum,
                                                    int* __restrict__ boff,
                                                    int* __restrict__ rowstart,
                                                    int NBLK, int Nn) {
  __shared__ int sh[256];
  const int t = threadIdx.x;
  sh[t] = (t < NBLK) ? bsum[t] : 0;
  __syncthreads();
  for (int d = 1; d < 256; d <<= 1) {
    int x = sh[t];
    int add = (t >= d) ? sh[t - d] : 0;
    __syncthreads();
    sh[t] = x + add;
    __syncthreads();
  }
  if (t < NBLK) boff[t] = (t == 0) ? 0 : sh[t - 1];
  if (t == NBLK - 1) rowstart[Nn] = sh[t];
}

__global__ __launch_bounds__(256) void scanC_kernel(const int* __restrict__ cnt,
                                                    const int* __restrict__ boff,
                                                    int* __restrict__ rowstart,
                                                    int* __restrict__ cursor, int Nn) {
  __shared__ int sh[256];
  const int t = threadIdx.x;
  const int base = blockIdx.x * 512 + t * 2;
  int a = (base < Nn) ? cnt[base] : 0;
  int b = (base + 1 < Nn) ? cnt[base + 1] : 0;
  sh[t] = a + b;
  __syncthreads();
  for (int d = 1; d < 256; d <<= 1) {
    int x = sh[t];
    int add = (t >= d) ? sh[t - d] : 0;
    __syncthreads();
    sh[t] = x + add;
    __syncthreads();
  }
  const int off = boff[blockIdx.x] + ((t == 0) ? 0 : sh[t - 1]);
  if (base < Nn) { rowstart[base] = off; cursor[base] = off; }
  if (base + 1 < Nn) { rowstart[base + 1] = off + a; cursor[base + 1] = off + a; }
}

// edge record: packed (src, norm) -> one 8B load per edge in the agg inner loop
__global__ void fill_kernel(const int* __restrict__ ei, int E, const float* __restrict__ dinv,
                            int* __restrict__ cursor, int2* __restrict__ erec) {
  int e = blockIdx.x * 256 + threadIdx.x;
  if (e < E) {
    int s = ei[e], d = ei[E + e];
    int pos = atomicAdd(&cursor[d], 1);
    union { float f; int i; } nv;
    nv.f = dinv[s] * dinv[d];
    erec[pos] = make_int2(s, nv.i);
  }
}

// W (K x N, f32, row-major) -> WT (N x K, bf16, row-major)
__global__ void wtrans_kernel(const float* __restrict__ W, unsigned short* __restrict__ WT,
                              int K, int N) {
  int i = blockIdx.x * 256 + threadIdx.x;
  if (i < K * N) {
    int n = i / K, k = i - n * K;
    WT[i] = f2b(W[k * N + n]);
  }
}

// ------------------- aggregation: out[n] = dinv[n]^2*in[n] + sum_e norm_e*in[src_e] -------------------
// One wave per node; 4-deep software-pipelined edge loop (round-10 proven variant).

template <int F, bool INF32>
__device__ __forceinline__ void rowload(const void* inv, int row, int base, float* r) {
  constexpr int V = F / 64;
  if constexpr (INF32) {
    const float* in = (const float*)inv + (size_t)row * F + base;
    if constexpr (V == 2) {
      float2 v = *(const float2*)in; r[0] = v.x; r[1] = v.y;
    } else {
      float4 v0 = *(const float4*)in; float4 v1 = *(const float4*)(in + 4);
      r[0] = v0.x; r[1] = v0.y; r[2] = v0.z; r[3] = v0.w;
      r[4] = v1.x; r[5] = v1.y; r[6] = v1.z; r[7] = v1.w;
    }
  } else {
    const unsigned short* in = (const unsigned short*)inv + (size_t)row * F + base;
    if constexpr (V == 2) {
      unsigned int v = *(const unsigned int*)in;
      r[0] = b2f(v & 0xffffu); r[1] = b2f(v >> 16);
    } else {
      bf16x8 v = *(const bf16x8*)in;
#pragma unroll
      for (int i = 0; i < 8; ++i) r[i] = b2f((unsigned short)v[i]);
    }
  }
}

template <int F, bool INF32, bool OUTF32, bool HASBIAS, bool DOGELU>
__global__ __launch_bounds__(256) void agg_kernel(
    const int* __restrict__ rowstart, const int2* __restrict__ erec,
    const float* __restrict__ dinv,
    const void* __restrict__ inv, const float* __restrict__ bias,
    void* __restrict__ outv, int Nn) {
  constexpr int V = F / 64;
  const int lane = threadIdx.x & 63;
  const int node = blockIdx.x * 4 + (threadIdx.x >> 6);
  if (node >= Nn) return;
  const int base = lane * V;
  float acc[V];
  {
    float w = dinv[node]; w = w * w;
    float rv[V];
    rowload<F, INF32>(inv, node, base, rv);
#pragma unroll
    for (int i = 0; i < V; ++i) acc[i] = w * rv[i];
  }
  const int e0 = rowstart[node], e1 = rowstart[node + 1];
  int e = e0;
  for (; e + 4 <= e1; e += 4) {
    int si[4]; float wi[4];
#pragma unroll
    for (int u = 0; u < 4; ++u) {
      int2 rec = erec[e + u];
      si[u] = rec.x;
      union { int i; float f; } nv; nv.i = rec.y; wi[u] = nv.f;
    }
    float rv[4][V];
#pragma unroll
    for (int u = 0; u < 4; ++u) rowload<F, INF32>(inv, si[u], base, rv[u]);
#pragma unroll
    for (int u = 0; u < 4; ++u)
#pragma unroll
      for (int i = 0; i < V; ++i) acc[i] += wi[u] * rv[u][i];
  }
  for (; e < e1; ++e) {
    int2 rec = erec[e];
    union { int i; float f; } nv; nv.i = rec.y;
    float rv[V];
    rowload<F, INF32>(inv, rec.x, base, rv);
#pragma unroll
    for (int i = 0; i < V; ++i) acc[i] += nv.f * rv[i];
  }
  if constexpr (HASBIAS) {
#pragma unroll
    for (int i = 0; i < V; ++i) acc[i] += bias[base + i];
  }
  if constexpr (DOGELU) {
#pragma unroll
    for (int i = 0; i < V; ++i) acc[i] = gelu_f(acc[i]);
  }
  if constexpr (OUTF32) {
    float* out = (float*)outv + (size_t)node * F + base;
#pragma unroll
    for (int i = 0; i < V; ++i) out[i] = acc[i];
  } else {
    unsigned short* out = (unsigned short*)outv + (size_t)node * F + base;
    if constexpr (V == 2) {
      unsigned int pack = (unsigned int)f2b(acc[0]) | ((unsigned int)f2b(acc[1]) << 16);
      *(unsigned int*)out = pack;
    } else {
      bf16x8 o;
#pragma unroll
      for (int i = 0; i < 8; ++i) o[i] = (short)f2b(acc[i]);
      *(bf16x8*)out = o;
    }
  }
}

// ------------------- GEMM 256x256, BK=32, 3 LDS buffers, counted-vmcnt (NO pinning) ----------
// C(M x N) = A(M x K) * BT(N x K)^T, bf16 in/out. M%256==0, N%256==0, K%32==0, K/32 >= 2.
// LDS 96 KiB: A[3][256*32] + B[3][256*32]. Slot swizzle pslot = slot ^ ((row>>1)&3) (0-conflict).
// Loop t: stage(t+2) -> compute(buf t%3) -> vmcnt(4) (t+1 confirmed; t+2's 4 stay in flight;
// NEVER 0 in steady state) -> raw s_barrier. Tail: vmcnt(0) once when no t+2 staged.
// WAR: stage(t+2) overwrites buf[(t-1)%3], whose readers all passed the end-of-(t-1) barrier.
// RAW: tile t+1's loads are vmcnt-confirmed + barrier-published before any wave reads them.
// No sched_barrier / setprio (m141 trap — implicated in round-5's regression).
// Epilogue: two 128-row half-passes through LDS, full-line dwordx4 stores (round-11 verified).

#define GLOAD16(gp, lp)                                                              \
  __builtin_amdgcn_global_load_lds((const __attribute__((address_space(1))) void*)(gp), \
                                   (__attribute__((address_space(3))) void*)(lp), 16, 0, 0)

template <bool HASBIAS, bool DOGELU>
__global__ __launch_bounds__(512, 2) void gemm256(
    const unsigned short* __restrict__ A, const unsigned short* __restrict__ BT,
    const float* __restrict__ bias, unsigned short* __restrict__ C,
    int N, int K, int NT) {
  __shared__ alignas(16) unsigned short smem[49152];  // 96 KiB
  unsigned short* As = smem;           // [3][256*32]
  unsigned short* Bs = smem + 24576;   // [3][256*32]
  const int tid = threadIdx.x;
  const int lane = tid & 63;
  const int wid = tid >> 6;
  const int wr = wid >> 2;   // 0..1 (128-row group)
  const int wc = wid & 3;    // 0..3 (64-col group)
  const int rr = lane & 15, rg = lane >> 4;

  const int G = gridDim.x;
  const int q = G >> 3, r = G & 7;
  const int xcd = blockIdx.x & 7, ii = blockIdx.x >> 3;
  const int w = (xcd < r ? xcd * (q + 1) : r * (q + 1) + (xcd - r) * q) + ii;
  const int bx = w / NT;
  const int by = w - bx * NT;
  const size_t brow = (size_t)bx * 256;
  const size_t bcol = (size_t)by * 256;

  const int nt = K >> 5;

  auto stage = [&](int t) {
    if (t >= nt) return;
    const int kb = t << 5;
    const int buf = t % 3;
#pragma unroll
    for (int j = 0; j < 2; ++j) {
      const int s = tid + 512 * j;     // 16B slot in [0,1024)
      const int row = s >> 2;          // 4 slots per row
      const int lslot = (s & 3) ^ ((row >> 1) & 3);  // inverse-swizzled source slot
      GLOAD16(A + (brow + row) * K + kb + lslot * 8, &As[buf * 8192 + s * 8]);
      GLOAD16(BT + (bcol + row) * K + kb + lslot * 8, &Bs[buf * 8192 + s * 8]);
    }
  };

  f32x4 acc[8][4] = {};
  stage(0);
  stage(1);
  asm volatile("s_waitcnt vmcnt(4)" ::: "memory");  // tile 0 landed (tile 1's 4 in flight)
  __builtin_amdgcn_s_barrier();

  for (int t = 0; t < nt; ++t) {
    stage(t + 2);
    const int buf = t % 3;
    bf16x8 bq[4];
#pragma unroll
    for (int nb = 0; nb < 4; ++nb) {
      const int R = wc * 64 + nb * 16 + rr;
      const int ps = rg ^ ((R >> 1) & 3);
      bq[nb] = *(const bf16x8*)(&Bs[buf * 8192 + R * 32 + ps * 8]);
    }
#pragma unroll
    for (int mb = 0; mb < 8; ++mb) {
      const int R = wr * 128 + mb * 16 + rr;
      const int ps = rg ^ ((R >> 1) & 3);
      bf16x8 a = *(const bf16x8*)(&As[buf * 8192 + R * 32 + ps * 8]);
#pragma unroll
      for (int nb = 0; nb < 4; ++nb)
        acc[mb][nb] = __builtin_amdgcn_mfma_f32_16x16x32_bf16(a, bq[nb], acc[mb][nb], 0, 0, 0);
    }
    if (t + 1 < nt) {
      if (t + 2 < nt)
        asm volatile("s_waitcnt vmcnt(4)" ::: "memory");  // t+1 confirmed, t+2 in flight
      else
        asm volatile("s_waitcnt vmcnt(0)" ::: "memory");  // tail: nothing newer, drain t+1
      __builtin_amdgcn_s_barrier();
    }
  }
  __syncthreads();  // publish last tile's reads before smem reuse

  // epilogue: two 128-row half-passes through LDS (64 KiB), full-line dwordx4 stores.
  char* Cl = (char*)smem;
#pragma unroll
  for (int half = 0; half < 2; ++half) {
    if (half) __syncthreads();  // previous half's reads done before overwrite
    if (wr == half) {
#pragma unroll
      for (int mb = 0; mb < 8; ++mb) {
        const int rowl0 = mb * 16 + rg * 4;  // local row within half [0,128)
#pragma unroll
        for (int nb = 0; nb < 4; ++nb) {
          const int coll = wc * 64 + nb * 16 + rr;
          float bv = 0.0f;
          if constexpr (HASBIAS) bv = bias[bcol + coll];
#pragma unroll
          for (int r2 = 0; r2 < 4; ++r2) {
            float v = acc[mb][nb][r2] + bv;
            if constexpr (DOGELU) v = gelu_f(v);
            const int rowl = rowl0 + r2;
            *(unsigned short*)(Cl + rowl * 512 + ((coll * 2) ^ ((rowl & 7) << 4))) = f2b(v);
          }
        }
      }
    }
    __syncthreads();
    const int rowl = tid >> 2;  // 0..127
    const int u = tid & 3;
    const size_t gbase = (brow + half * 128 + rowl) * (size_t)N + bcol;
#pragma unroll
    for (int c = 0; c < 8; ++c) {
      uint4 v = *(const uint4*)(Cl + rowl * 512 + ((c * 64 + u * 16) ^ ((rowl & 7) << 4)));
      *(uint4*)(&C[gbase + c * 32 + u * 8]) = v;
    }
  }
}

// ------------------- GEMM 128x128 (m97-style) for K=128 / small-N layers -------------------

template <bool HASBIAS, bool DOGELU>
__global__ __launch_bounds__(256) void gemm_bt(
    const unsigned short* __restrict__ A, const unsigned short* __restrict__ BT,
    const float* __restrict__ bias, unsigned short* __restrict__ C,
    int N, int K, int NT) {
  __shared__ alignas(16) unsigned short Asl[128 * 32];
  __shared__ alignas(16) unsigned short Bsl[128 * 32];
  const int tid = threadIdx.x;
  const int lane = tid & 63;
  const int wid = tid >> 6;

  const int G = gridDim.x;
  const int q = G >> 3, r = G & 7;
  const int xcd = blockIdx.x & 7, ii = blockIdx.x >> 3;
  const int w = (xcd < r ? xcd * (q + 1) : r * (q + 1) + (xcd - r) * q) + ii;
  const int bx = w / NT;
  const int by = w - bx * NT;

  const size_t brow = (size_t)bx * 128;
  const size_t bcol = (size_t)by * 128;
  const int wr = (wid >> 1) * 64;
  const int wc = (wid & 1) * 64;
  const int rr = lane & 15, rg = lane >> 4;
  f32x4 acc[4][4] = {};
  const int KT = K >> 5;
  for (int kt = 0; kt < KT; ++kt) {
    const int kb = kt << 5;
#pragma unroll
    for (int rsub = 0; rsub < 2; ++rsub) {
      const int c = tid + rsub * 256;
      const int arow = c >> 2;
      const int jlog = (c & 3) ^ ((arow >> 1) & 3);
      GLOAD16(A + (brow + arow) * K + kb + jlog * 8, &Asl[c * 8]);
      GLOAD16(BT + (bcol + arow) * K + kb + jlog * 8, &Bsl[c * 8]);
    }
    __syncthreads();
    bf16x8 af[4], bfr[4];
#pragma unroll
    for (int m = 0; m < 4; ++m) {
      const int R = wr + m * 16 + rr;
      af[m] = *(const bf16x8*)(&Asl[R * 32 + ((rg ^ ((R >> 1) & 3)) * 8)]);
    }
#pragma unroll
    for (int n = 0; n < 4; ++n) {
      const int R = wc + n * 16 + rr;
      bfr[n] = *(const bf16x8*)(&Bsl[R * 32 + ((rg ^ ((R >> 1) & 3)) * 8)]);
    }
#pragma unroll
    for (int m = 0; m < 4; ++m)
#pragma unroll
      for (int n = 0; n < 4; ++n)
        acc[m][n] = __builtin_amdgcn_mfma_f32_16x16x32_bf16(af[m], bfr[n], acc[m][n], 0, 0, 0);
    __syncthreads();
  }
#pragma unroll
  for (int m = 0; m < 4; ++m) {
    size_t row0 = brow + wr + m * 16 + rg * 4;
#pragma unroll
    for (int n = 0; n < 4; ++n) {
      size_t col = bcol + wc + n * 16 + rr;
      float bv = 0.0f;
      if constexpr (HASBIAS) bv = bias[col];
#pragma unroll
      for (int r2 = 0; r2 < 4; ++r2) {
        float v = acc[m][n][r2] + bv;
        if constexpr (DOGELU) v = gelu_f(v);
        C[(row0 + r2) * N + col] = f2b(v);
      }
    }
  }
}

// ------------------- launch -------------------

extern "C" void kernel_launch(void* const* d_in, const int* in_sizes, int n_in,
                              void* d_out, int out_size, void* d_ws, size_t ws_size,
                              hipStream_t stream) {
  const float* x = (const float*)d_in[0];
  const int* ei = (const int*)d_in[1];
  const float* W1 = (const float*)d_in[2]; const float* b1 = (const float*)d_in[3];
  const float* W2 = (const float*)d_in[4]; const float* b2 = (const float*)d_in[5];
  const float* W3 = (const float*)d_in[6]; const float* b3 = (const float*)d_in[7];
  const float* W4 = (const float*)d_in[8]; const float* b4 = (const float*)d_in[9];

  const int Nn = in_sizes[0] / 128;   // 100000
  const int E = in_sizes[1] / 2;      // 500000
  const int Mpad = (Nn + 255) & ~255; // 100096 = 391*256

  char* p = (char*)d_ws;
  auto alloc = [&](size_t bytes) {
    char* r = p;
    p += (bytes + 255) & ~(size_t)255;
    return r;
  };
  float* dinv = (float*)alloc((size_t)Nn * 4);
  int* cnt = (int*)alloc((size_t)Nn * 4);
  int* rowstart = (int*)alloc((size_t)(Nn + 1) * 4);
  int* cursor = (int*)alloc((size_t)Nn * 4);
  int2* erec = (int2*)alloc((size_t)E * 8);
  int* bsum = (int*)alloc((size_t)256 * 4);
  int* boff = (int*)alloc((size_t)256 * 4);
  unsigned short* WT1 = (unsigned short*)alloc((size_t)512 * 128 * 2);
  unsigned short* WT2 = (unsigned short*)alloc((size_t)768 * 512 * 2);
  unsigned short* WT3 = (unsigned short*)alloc((size_t)512 * 768 * 2);
  unsigned short* WT4 = (unsigned short*)alloc((size_t)128 * 512 * 2);
  unsigned short* bufA = (unsigned short*)alloc((size_t)Mpad * 512 * 2);
  unsigned short* bufB = (unsigned short*)alloc((size_t)Mpad * 768 * 2);
  unsigned short* xb = bufB;  // x-bf16 scratch; consumed before L1 gemm writes bufB

  const int EB = (E + 255) / 256;
  const int NB = (Nn + 255) / 256;
  const int AGGB = (Nn + 3) / 4;
  const int MT256 = Mpad / 256;  // 391
  const int MT128 = Mpad / 128;
  const int NSCAN = (Nn + 511) / 512;

  hipMemsetAsync(cnt, 0, (size_t)Nn * 4, stream);
  count_kernel<<<EB, 256, 0, stream>>>(ei, E, cnt);
  dinv_kernel<<<NB, 256, 0, stream>>>(cnt, dinv, Nn);
  scanA_kernel<<<NSCAN, 256, 0, stream>>>(cnt, bsum, Nn);
  scanB_kernel<<<1, 256, 0, stream>>>(bsum, boff, rowstart, NSCAN, Nn);
  scanC_kernel<<<NSCAN, 256, 0, stream>>>(cnt, boff, rowstart, cursor, Nn);
  fill_kernel<<<EB, 256, 0, stream>>>(ei, E, dinv, cursor, erec);
  wtrans_kernel<<<(128 * 512 + 255) / 256, 256, 0, stream>>>(W1, WT1, 128, 512);
  wtrans_kernel<<<(512 * 768 + 255) / 256, 256, 0, stream>>>(W2, WT2, 512, 768);
  wtrans_kernel<<<(768 * 512 + 255) / 256, 256, 0, stream>>>(W3, WT3, 768, 512);
  wtrans_kernel<<<(512 * 128 + 255) / 256, 256, 0, stream>>>(W4, WT4, 512, 128);
  xcast_kernel<<<(Nn * 16 + 255) / 256, 256, 0, stream>>>(x, xb, Nn * 16);

  // L1: a1 = Ahat @ x_bf16 (F=128); h1 = gelu(a1@W1 + b1)  [K=128 -> gemm_bt, round-10 config]
  agg_kernel<128, false, false, false, false><<<AGGB, 256, 0, stream>>>(
      rowstart, erec, dinv, xb, nullptr, bufA, Nn);
  gemm_bt<true, true><<<MT128 * 4, 256, 0, stream>>>(bufA, WT1, b1, bufB, 512, 128, 4);

  // L2: a2 = Ahat @ h1 (F=512); h2 = gelu(a2@W2 + b2)
  agg_kernel<512, false, false, false, false><<<AGGB, 256, 0, stream>>>(
      rowstart, erec, dinv, bufB, nullptr, bufA, Nn);
  gemm256<true, true><<<MT256 * 3, 512, 0, stream>>>(bufA, WT2, b2, bufB, 768, 512, 3);

  // L3: g3 = h2@W3 (no epi); h3 = gelu(Ahat@g3 + b3)
  gemm256<false, false><<<MT256 * 2, 512, 0, stream>>>(bufB, WT3, nullptr, bufA, 512, 768, 2);
  agg_kernel<512, false, false, true, true><<<AGGB, 256, 0, stream>>>(
      rowstart, erec, dinv, bufA, b3, bufB, Nn);

  // L4: g4 = h3@W4 (no epi); out = Ahat@g4 + b4 (f32 out)
  gemm_bt<false, false><<<MT128 * 1, 256, 0, stream>>>(bufB, WT4, nullptr, bufA, 128, 512, 1);
  agg_kernel<128, false, true, true, false><<<AGGB, 256, 0, stream>>>(
      rowstart, erec, dinv, bufA, b4, d_out, Nn);
}

// Round 15
// 704.519 us; speedup vs baseline: 1.1362x; 1.1362x over previous
//
#include <hip/hip_runtime.h>

typedef short bf16x8 __attribute__((ext_vector_type(8)));
typedef float f32x4 __attribute__((ext_vector_type(4)));

__device__ __forceinline__ float b2f(unsigned short u) {
  union { unsigned int i; float f; } x; x.i = ((unsigned int)u) << 16; return x.f;
}
__device__ __forceinline__ unsigned short f2b(float f) {
  union { float f; unsigned int u; } x; x.f = f;
  unsigned int r = (x.u + 0x7FFFu + ((x.u >> 16) & 1u)) >> 16;
  return (unsigned short)r;
}
__device__ __forceinline__ float gelu_f(float v) {
  return 0.5f * v * (1.0f + erff(v * 0.70710678118654752440f));
}

// ------------------- setup kernels -------------------

__global__ void count_kernel(const int* __restrict__ ei, int E, int* __restrict__ cnt) {
  int e = blockIdx.x * 256 + threadIdx.x;
  if (e < E) atomicAdd(&cnt[ei[E + e]], 1);
}

__global__ void dinv_kernel(const int* __restrict__ cnt, float* __restrict__ dinv, int Nn) {
  int n = blockIdx.x * 256 + threadIdx.x;
  if (n < Nn) dinv[n] = rsqrtf((float)cnt[n] + 1.0f);  // +1 self-loop
}

// x (f32) -> bf16, 8 elems/thread
__global__ void xcast_kernel(const float* __restrict__ x, unsigned short* __restrict__ xb,
                             int total8) {
  int i = blockIdx.x * 256 + threadIdx.x;
  if (i < total8) {
    float4 a = *(const float4*)(x + (size_t)i * 8);
    float4 b = *(const float4*)(x + (size_t)i * 8 + 4);
    bf16x8 o;
    o[0] = (short)f2b(a.x); o[1] = (short)f2b(a.y); o[2] = (short)f2b(a.z); o[3] = (short)f2b(a.w);
    o[4] = (short)f2b(b.x); o[5] = (short)f2b(b.y); o[6] = (short)f2b(b.z); o[7] = (short)f2b(b.w);
    *(bf16x8*)(xb + (size_t)i * 8) = o;
  }
}

// ---- multi-block exclusive scan of cnt[0..Nn) -> rowstart/cursor (3 passes) ----

__global__ __launch_bounds__(256) void scanA_kernel(const int* __restrict__ cnt,
                                                    int* __restrict__ bsum, int Nn) {
  __shared__ int red[256];
  const int t = threadIdx.x;
  const int base = blockIdx.x * 512 + t * 2;
  int a = (base < Nn) ? cnt[base] : 0;
  int b = (base + 1 < Nn) ? cnt[base + 1] : 0;
  red[t] = a + b;
  __syncthreads();
  for (int d = 128; d > 0; d >>= 1) {
    if (t < d) red[t] += red[t + d];
    __syncthreads();
  }
  if (t == 0) bsum[blockIdx.x] = red[0];
}

__global__ __launch_bounds__(256) void scanB_kernel(const int* __restrict__ bsum,
                                                    int* __restrict__ boff,
                                                    int* __restrict__ rowstart,
                                                    int NBLK, int Nn) {
  __shared__ int sh[256];
  const int t = threadIdx.x;
  sh[t] = (t < NBLK) ? bsum[t] : 0;
  __syncthreads();
  for (int d = 1; d < 256; d <<= 1) {
    int x = sh[t];
    int add = (t >= d) ? sh[t - d] : 0;
    __syncthreads();
    sh[t] = x + add;
    __syncthreads();
  }
  if (t < NBLK) boff[t] = (t == 0) ? 0 : sh[t - 1];
  if (t == NBLK - 1) rowstart[Nn] = sh[t];
}

__global__ __launch_bounds__(256) void scanC_kernel(const int* __restrict__ cnt,
                                                    const int* __restrict__ boff,
                                                    int* __restrict__ rowstart,
                                                    int* __restrict__ cursor, int Nn) {
  __shared__ int sh[256];
  const int t = threadIdx.x;
  const int base = blockIdx.x * 512 + t * 2;
  int a = (base < Nn) ? cnt[base] : 0;
  int b = (base + 1 < Nn) ? cnt[base + 1] : 0;
  sh[t] = a + b;
  __syncthreads();
  for (int d = 1; d < 256; d <<= 1) {
    int x = sh[t];
    int add = (t >= d) ? sh[t - d] : 0;
    __syncthreads();
    sh[t] = x + add;
    __syncthreads();
  }
  const int off = boff[blockIdx.x] + ((t == 0) ? 0 : sh[t - 1]);
  if (base < Nn) { rowstart[base] = off; cursor[base] = off; }
  if (base + 1 < Nn) { rowstart[base + 1] = off + a; cursor[base + 1] = off + a; }
}

// edge record: packed (src, norm) -> one 8B load per edge in the agg inner loop
__global__ void fill_kernel(const int* __restrict__ ei, int E, const float* __restrict__ dinv,
                            int* __restrict__ cursor, int2* __restrict__ erec) {
  int e = blockIdx.x * 256 + threadIdx.x;
  if (e < E) {
    int s = ei[e], d = ei[E + e];
    int pos = atomicAdd(&cursor[d], 1);
    union { float f; int i; } nv;
    nv.f = dinv[s] * dinv[d];
    erec[pos] = make_int2(s, nv.i);
  }
}

// all 4 weights W (K x N, f32, row-major) -> WT (N x K, bf16, row-major), one launch.
// segment boundaries (element counts): W1 64K | W2 384K | W3 384K | W4 64K
__global__ void wtrans_all_kernel(const float* __restrict__ W1, unsigned short* __restrict__ WT1,
                                  const float* __restrict__ W2, unsigned short* __restrict__ WT2,
                                  const float* __restrict__ W3, unsigned short* __restrict__ WT3,
                                  const float* __restrict__ W4, unsigned short* __restrict__ WT4) {
  int i = blockIdx.x * 256 + threadIdx.x;
  const float* W; unsigned short* WT; int K, N;
  if (i < 65536)            { W = W1; WT = WT1; K = 128; N = 512; }
  else if (i < 458752)      { W = W2; WT = WT2; K = 512; N = 768; i -= 65536; }
  else if (i < 851968)      { W = W3; WT = WT3; K = 768; N = 512; i -= 458752; }
  else if (i < 917504)      { W = W4; WT = WT4; K = 512; N = 128; i -= 851968; }
  else return;
  int n = i / K, k = i - n * K;
  WT[i] = f2b(W[k * N + n]);
}

// ------------------- aggregation: out[n] = dinv[n]^2*in[n] + sum_e norm_e*in[src_e] -------------------
// One wave per node; 4-deep software-pipelined edge loop (round-10 proven variant).

template <int F, bool INF32>
__device__ __forceinline__ void rowload(const void* inv, int row, int base, float* r) {
  constexpr int V = F / 64;
  if constexpr (INF32) {
    const float* in = (const float*)inv + (size_t)row * F + base;
    if constexpr (V == 2) {
      float2 v = *(const float2*)in; r[0] = v.x; r[1] = v.y;
    } else {
      float4 v0 = *(const float4*)in; float4 v1 = *(const float4*)(in + 4);
      r[0] = v0.x; r[1] = v0.y; r[2] = v0.z; r[3] = v0.w;
      r[4] = v1.x; r[5] = v1.y; r[6] = v1.z; r[7] = v1.w;
    }
  } else {
    const unsigned short* in = (const unsigned short*)inv + (size_t)row * F + base;
    if constexpr (V == 2) {
      unsigned int v = *(const unsigned int*)in;
      r[0] = b2f(v & 0xffffu); r[1] = b2f(v >> 16);
    } else {
      bf16x8 v = *(const bf16x8*)in;
#pragma unroll
      for (int i = 0; i < 8; ++i) r[i] = b2f((unsigned short)v[i]);
    }
  }
}

template <int F, bool INF32, bool OUTF32, bool HASBIAS, bool DOGELU>
__global__ __launch_bounds__(256) void agg_kernel(
    const int* __restrict__ rowstart, const int2* __restrict__ erec,
    const float* __restrict__ dinv,
    const void* __restrict__ inv, const float* __restrict__ bias,
    void* __restrict__ outv, int Nn) {
  constexpr int V = F / 64;
  const int lane = threadIdx.x & 63;
  const int node = blockIdx.x * 4 + (threadIdx.x >> 6);
  if (node >= Nn) return;
  const int base = lane * V;
  float acc[V];
  {
    float w = dinv[node]; w = w * w;
    float rv[V];
    rowload<F, INF32>(inv, node, base, rv);
#pragma unroll
    for (int i = 0; i < V; ++i) acc[i] = w * rv[i];
  }
  const int e0 = rowstart[node], e1 = rowstart[node + 1];
  int e = e0;
  for (; e + 4 <= e1; e += 4) {
    int si[4]; float wi[4];
#pragma unroll
    for (int u = 0; u < 4; ++u) {
      int2 rec = erec[e + u];
      si[u] = rec.x;
      union { int i; float f; } nv; nv.i = rec.y; wi[u] = nv.f;
    }
    float rv[4][V];
#pragma unroll
    for (int u = 0; u < 4; ++u) rowload<F, INF32>(inv, si[u], base, rv[u]);
#pragma unroll
    for (int u = 0; u < 4; ++u)
#pragma unroll
      for (int i = 0; i < V; ++i) acc[i] += wi[u] * rv[u][i];
  }
  for (; e < e1; ++e) {
    int2 rec = erec[e];
    union { int i; float f; } nv; nv.i = rec.y;
    float rv[V];
    rowload<F, INF32>(inv, rec.x, base, rv);
#pragma unroll
    for (int i = 0; i < V; ++i) acc[i] += nv.f * rv[i];
  }
  if constexpr (HASBIAS) {
#pragma unroll
    for (int i = 0; i < V; ++i) acc[i] += bias[base + i];
  }
  if constexpr (DOGELU) {
#pragma unroll
    for (int i = 0; i < V; ++i) acc[i] = gelu_f(acc[i]);
  }
  if constexpr (OUTF32) {
    float* out = (float*)outv + (size_t)node * F + base;
#pragma unroll
    for (int i = 0; i < V; ++i) out[i] = acc[i];
  } else {
    unsigned short* out = (unsigned short*)outv + (size_t)node * F + base;
    if constexpr (V == 2) {
      unsigned int pack = (unsigned int)f2b(acc[0]) | ((unsigned int)f2b(acc[1]) << 16);
      *(unsigned int*)out = pack;
    } else {
      bf16x8 o;
#pragma unroll
      for (int i = 0; i < 8; ++i) o[i] = (short)f2b(acc[i]);
      *(bf16x8*)out = o;
    }
  }
}

// ------------------- GEMM 256x256 tile, BK=64, 8 waves, double-buffered 2-phase -------------------
// Best-measured variant across 8 tested structures (144-150 us at L2/L3 shapes).
// Constraint analysis: intensity = 128 FLOP/staged-byte; observed ~546 TF => ~4.2 TB/s operand
// delivery — schedule-insensitive (BK=32 variants all 242 us, 8-phase/counted-vmcnt neutral).

#define GLOAD16(gp, lp)                                                              \
  __builtin_amdgcn_global_load_lds((const __attribute__((address_space(1))) void*)(gp), \
                                   (__attribute__((address_space(3))) void*)(lp), 16, 0, 0)

template <bool HASBIAS, bool DOGELU>
__global__ __launch_bounds__(512, 2) void gemm256(
    const unsigned short* __restrict__ A, const unsigned short* __restrict__ BT,
    const float* __restrict__ bias, unsigned short* __restrict__ C,
    int N, int K, int NT) {
  __shared__ alignas(16) unsigned short smem[65536];  // 128 KiB
  unsigned short* As = smem;          // [2][256*64]
  unsigned short* Bs = smem + 32768;  // [2][256*64]
  const int tid = threadIdx.x;
  const int lane = tid & 63;
  const int wid = tid >> 6;
  const int wr = wid >> 2;
  const int wc = wid & 3;
  const int rr = lane & 15, rg = lane >> 4;

  const int G = gridDim.x;
  const int q = G >> 3, r = G & 7;
  const int xcd = blockIdx.x & 7, ii = blockIdx.x >> 3;
  const int w = (xcd < r ? xcd * (q + 1) : r * (q + 1) + (xcd - r) * q) + ii;
  const int bx = w / NT;
  const int by = w - bx * NT;
  const size_t brow = (size_t)bx * 256;
  const size_t bcol = (size_t)by * 256;

  const int nt = K >> 6;

  auto stage = [&](int t) {
    const int kb = t << 6;
    const int buf = t & 1;
#pragma unroll
    for (int j = 0; j < 4; ++j) {
      const int s = tid + 512 * j;
      const int row = s >> 3;
      const int lslot = (s & 7) ^ (row & 7);
      GLOAD16(A + (brow + row) * K + kb + lslot * 8, &As[buf * 16384 + s * 8]);
      GLOAD16(BT + (bcol + row) * K + kb + lslot * 8, &Bs[buf * 16384 + s * 8]);
    }
  };

  f32x4 acc[8][4] = {};
  stage(0);
  __syncthreads();
  for (int t = 0; t < nt; ++t) {
    if (t + 1 < nt) stage(t + 1);
    const int buf = t & 1;
    bf16x8 bq[2][4];
#pragma unroll
    for (int kk = 0; kk < 2; ++kk)
#pragma unroll
      for (int nb = 0; nb < 4; ++nb) {
        const int R = wc * 64 + nb * 16 + rr;
        const int ps = (kk * 4 + rg) ^ (R & 7);
        bq[kk][nb] = *(const bf16x8*)(&Bs[buf * 16384 + R * 64 + ps * 8]);
      }
#pragma unroll
    for (int mb = 0; mb < 8; ++mb) {
      const int R = wr * 128 + mb * 16 + rr;
      const int ps0 = rg ^ (R & 7);
      const int ps1 = (4 + rg) ^ (R & 7);
      bf16x8 a0 = *(const bf16x8*)(&As[buf * 16384 + R * 64 + ps0 * 8]);
      bf16x8 a1 = *(const bf16x8*)(&As[buf * 16384 + R * 64 + ps1 * 8]);
#pragma unroll
      for (int nb = 0; nb < 4; ++nb)
        acc[mb][nb] = __builtin_amdgcn_mfma_f32_16x16x32_bf16(a0, bq[0][nb], acc[mb][nb], 0, 0, 0);
#pragma unroll
      for (int nb = 0; nb < 4; ++nb)
        acc[mb][nb] = __builtin_amdgcn_mfma_f32_16x16x32_bf16(a1, bq[1][nb], acc[mb][nb], 0, 0, 0);
    }
    __syncthreads();
  }

  // epilogue: LDS-staged full-line writeback
  char* Cl = (char*)smem;
#pragma unroll
  for (int mb = 0; mb < 8; ++mb) {
    const int rowl0 = wr * 128 + mb * 16 + rg * 4;
#pragma unroll
    for (int nb = 0; nb < 4; ++nb) {
      const int coll = wc * 64 + nb * 16 + rr;
      float bv = 0.0f;
      if constexpr (HASBIAS) bv = bias[bcol + coll];
#pragma unroll
      for (int r2 = 0; r2 < 4; ++r2) {
        float v = acc[mb][nb][r2] + bv;
        if constexpr (DOGELU) v = gelu_f(v);
        const int rowl = rowl0 + r2;
        *(unsigned short*)(Cl + rowl * 512 + ((coll * 2) ^ ((rowl & 7) << 4))) = f2b(v);
      }
    }
  }
  __syncthreads();
#pragma unroll
  for (int pass = 0; pass < 2; ++pass) {
    const int rowl = pass * 128 + (tid >> 2);
    const int u = tid & 3;
    const size_t gbase = (brow + rowl) * (size_t)N + bcol;
#pragma unroll
    for (int c = 0; c < 8; ++c) {
      uint4 v = *(const uint4*)(Cl + rowl * 512 + ((c * 64 + u * 16) ^ ((rowl & 7) << 4)));
      *(uint4*)(&C[gbase + c * 32 + u * 8]) = v;
    }
  }
}

// ------------------- GEMM 128x128 (m97-style) for K=128 / small-N layers -------------------

template <bool HASBIAS, bool DOGELU>
__global__ __launch_bounds__(256) void gemm_bt(
    const unsigned short* __restrict__ A, const unsigned short* __restrict__ BT,
    const float* __restrict__ bias, unsigned short* __restrict__ C,
    int N, int K, int NT) {
  __shared__ alignas(16) unsigned short Asl[128 * 32];
  __shared__ alignas(16) unsigned short Bsl[128 * 32];
  const int tid = threadIdx.x;
  const int lane = tid & 63;
  const int wid = tid >> 6;

  const int G = gridDim.x;
  const int q = G >> 3, r = G & 7;
  const int xcd = blockIdx.x & 7, ii = blockIdx.x >> 3;
  const int w = (xcd < r ? xcd * (q + 1) : r * (q + 1) + (xcd - r) * q) + ii;
  const int bx = w / NT;
  const int by = w - bx * NT;

  const size_t brow = (size_t)bx * 128;
  const size_t bcol = (size_t)by * 128;
  const int wr = (wid >> 1) * 64;
  const int wc = (wid & 1) * 64;
  const int rr = lane & 15, rg = lane >> 4;
  f32x4 acc[4][4] = {};
  const int KT = K >> 5;
  for (int kt = 0; kt < KT; ++kt) {
    const int kb = kt << 5;
#pragma unroll
    for (int rsub = 0; rsub < 2; ++rsub) {
      const int c = tid + rsub * 256;
      const int arow = c >> 2;
      const int jlog = (c & 3) ^ ((arow >> 1) & 3);
      GLOAD16(A + (brow + arow) * K + kb + jlog * 8, &Asl[c * 8]);
      GLOAD16(BT + (bcol + arow) * K + kb + jlog * 8, &Bsl[c * 8]);
    }
    __syncthreads();
    bf16x8 af[4], bfr[4];
#pragma unroll
    for (int m = 0; m < 4; ++m) {
      const int R = wr + m * 16 + rr;
      af[m] = *(const bf16x8*)(&Asl[R * 32 + ((rg ^ ((R >> 1) & 3)) * 8)]);
    }
#pragma unroll
    for (int n = 0; n < 4; ++n) {
      const int R = wc + n * 16 + rr;
      bfr[n] = *(const bf16x8*)(&Bsl[R * 32 + ((rg ^ ((R >> 1) & 3)) * 8)]);
    }
#pragma unroll
    for (int m = 0; m < 4; ++m)
#pragma unroll
      for (int n = 0; n < 4; ++n)
        acc[m][n] = __builtin_amdgcn_mfma_f32_16x16x32_bf16(af[m], bfr[n], acc[m][n], 0, 0, 0);
    __syncthreads();
  }
#pragma unroll
  for (int m = 0; m < 4; ++m) {
    size_t row0 = brow + wr + m * 16 + rg * 4;
#pragma unroll
    for (int n = 0; n < 4; ++n) {
      size_t col = bcol + wc + n * 16 + rr;
      float bv = 0.0f;
      if constexpr (HASBIAS) bv = bias[col];
#pragma unroll
      for (int r2 = 0; r2 < 4; ++r2) {
        float v = acc[m][n][r2] + bv;
        if constexpr (DOGELU) v = gelu_f(v);
        C[(row0 + r2) * N + col] = f2b(v);
      }
    }
  }
}

// ------------------- launch -------------------

extern "C" void kernel_launch(void* const* d_in, const int* in_sizes, int n_in,
                              void* d_out, int out_size, void* d_ws, size_t ws_size,
                              hipStream_t stream) {
  const float* x = (const float*)d_in[0];
  const int* ei = (const int*)d_in[1];
  const float* W1 = (const float*)d_in[2]; const float* b1 = (const float*)d_in[3];
  const float* W2 = (const float*)d_in[4]; const float* b2 = (const float*)d_in[5];
  const float* W3 = (const float*)d_in[6]; const float* b3 = (const float*)d_in[7];
  const float* W4 = (const float*)d_in[8]; const float* b4 = (const float*)d_in[9];

  const int Nn = in_sizes[0] / 128;   // 100000
  const int E = in_sizes[1] / 2;      // 500000
  const int Mpad = (Nn + 255) & ~255; // 100096 = 391*256

  char* p = (char*)d_ws;
  auto alloc = [&](size_t bytes) {
    char* r = p;
    p += (bytes + 255) & ~(size_t)255;
    return r;
  };
  float* dinv = (float*)alloc((size_t)Nn * 4);
  int* cnt = (int*)alloc((size_t)Nn * 4);
  int* rowstart = (int*)alloc((size_t)(Nn + 1) * 4);
  int* cursor = (int*)alloc((size_t)Nn * 4);
  int2* erec = (int2*)alloc((size_t)E * 8);
  int* bsum = (int*)alloc((size_t)256 * 4);
  int* boff = (int*)alloc((size_t)256 * 4);
  unsigned short* WT1 = (unsigned short*)alloc((size_t)512 * 128 * 2);
  unsigned short* WT2 = (unsigned short*)alloc((size_t)768 * 512 * 2);
  unsigned short* WT3 = (unsigned short*)alloc((size_t)512 * 768 * 2);
  unsigned short* WT4 = (unsigned short*)alloc((size_t)128 * 512 * 2);
  unsigned short* bufA = (unsigned short*)alloc((size_t)Mpad * 512 * 2);
  unsigned short* bufB = (unsigned short*)alloc((size_t)Mpad * 768 * 2);
  unsigned short* xb = bufB;  // x-bf16 scratch; consumed before L1 gemm writes bufB

  const int EB = (E + 255) / 256;
  const int NB = (Nn + 255) / 256;
  const int AGGB = (Nn + 3) / 4;
  const int MT256 = Mpad / 256;  // 391
  const int MT128 = Mpad / 128;
  const int NSCAN = (Nn + 511) / 512;

  hipMemsetAsync(cnt, 0, (size_t)Nn * 4, stream);
  count_kernel<<<EB, 256, 0, stream>>>(ei, E, cnt);
  dinv_kernel<<<NB, 256, 0, stream>>>(cnt, dinv, Nn);
  scanA_kernel<<<NSCAN, 256, 0, stream>>>(cnt, bsum, Nn);
  scanB_kernel<<<1, 256, 0, stream>>>(bsum, boff, rowstart, NSCAN, Nn);
  scanC_kernel<<<NSCAN, 256, 0, stream>>>(cnt, boff, rowstart, cursor, Nn);
  fill_kernel<<<EB, 256, 0, stream>>>(ei, E, dinv, cursor, erec);
  wtrans_all_kernel<<<(917504 + 255) / 256, 256, 0, stream>>>(W1, WT1, W2, WT2, W3, WT3, W4, WT4);
  xcast_kernel<<<(Nn * 16 + 255) / 256, 256, 0, stream>>>(x, xb, Nn * 16);

  // L1: a1 = Ahat @ x_bf16 (F=128); h1 = gelu(a1@W1 + b1)  [K=128 -> gemm_bt, round-10 config]
  agg_kernel<128, false, false, false, false><<<AGGB, 256, 0, stream>>>(
      rowstart, erec, dinv, xb, nullptr, bufA, Nn);
  gemm_bt<true, true><<<MT128 * 4, 256, 0, stream>>>(bufA, WT1, b1, bufB, 512, 128, 4);

  // L2: a2 = Ahat @ h1 (F=512); h2 = gelu(a2@W2 + b2)
  agg_kernel<512, false, false, false, false><<<AGGB, 256, 0, stream>>>(
      rowstart, erec, dinv, bufB, nullptr, bufA, Nn);
  gemm256<true, true><<<MT256 * 3, 512, 0, stream>>>(bufA, WT2, b2, bufB, 768, 512, 3);

  // L3: g3 = h2@W3 (no epi); h3 = gelu(Ahat@g3 + b3)
  gemm256<false, false><<<MT256 * 2, 512, 0, stream>>>(bufB, WT3, nullptr, bufA, 512, 768, 2);
  agg_kernel<512, false, false, true, true><<<AGGB, 256, 0, stream>>>(
      rowstart, erec, dinv, bufA, b3, bufB, Nn);

  // L4: g4 = h3@W4 (no epi); out = Ahat@g4 + b4 (f32 out)
  gemm_bt<false, false><<<MT128 * 1, 256, 0, stream>>>(bufB, WT4, nullptr, bufA, 128, 512, 1);
  agg_kernel<128, false, true, true, false><<<AGGB, 256, 0, stream>>>(
      rowstart, erec, dinv, bufA, b4, d_out, Nn);
}